// Round 5
// baseline (100.851 us; speedup 1.0000x reference)
//
#include <hip/hip_runtime.h>
#include <math.h>
#include <stdint.h>

#define IN_DIM  256
#define OUT_DIM 256
#define NROWS   68     // G + K
#define NT      71     // knot count
#define BATCH   512
#define W_ELEMS (NROWS * IN_DIM * OUT_DIM)    // 4,456,448
#define PART_FLOATS (16 * BATCH * OUT_DIM)    // 16 c-chunk slices = 8 MB

// ---- Kernel A: convert w fp32 -> packed bf16 pairs (streaming, ~4.5 us) ----
__device__ __forceinline__ uint32_t bf16_rne(float f) {
  uint32_t u = __builtin_bit_cast(uint32_t, f);
  return (u + 0x7fffu + ((u >> 16) & 1u)) >> 16;   // finite inputs only
}

__global__ __launch_bounds__(256) void cvt_kernel(const float* __restrict__ w,
                                                  uint32_t* __restrict__ wb) {
  const int base = (blockIdx.x * 256 + threadIdx.x) * 8;   // 8 floats / thread
  const float4 a = *(const float4*)(w + base);
  const float4 b = *(const float4*)(w + base + 4);
  uint4 o;
  o.x = bf16_rne(a.x) | (bf16_rne(a.y) << 16);
  o.y = bf16_rne(a.z) | (bf16_rne(a.w) << 16);
  o.z = bf16_rne(b.x) | (bf16_rne(b.y) << 16);
  o.w = bf16_rne(b.z) | (bf16_rne(b.w) << 16);
  *(uint4*)(wb + base / 2) = o;
}

// ---- Kernel B: bf16 gather-accumulate.
//      Block = 8 batch rows x 16 channels (grid 1024 -> 4 blocks/CU, double
//      R1's occupancy). Inner loop identical to the proven R1 code: half-wave
//      = one channel (32 lanes x uint4 = full 256-o bf16 row), compiler-
//      scheduled loads, full cross-b L1/MSHR dedup preserved. ----
__device__ __forceinline__ void fma8(const uint4 q, const float y, float* acc) {
  acc[0] += y * __builtin_bit_cast(float, q.x << 16);
  acc[1] += y * __builtin_bit_cast(float, q.x & 0xffff0000u);
  acc[2] += y * __builtin_bit_cast(float, q.y << 16);
  acc[3] += y * __builtin_bit_cast(float, q.y & 0xffff0000u);
  acc[4] += y * __builtin_bit_cast(float, q.z << 16);
  acc[5] += y * __builtin_bit_cast(float, q.z & 0xffff0000u);
  acc[6] += y * __builtin_bit_cast(float, q.w << 16);
  acc[7] += y * __builtin_bit_cast(float, q.w & 0xffff0000u);
}

__global__ __launch_bounds__(256, 4) void kan_gather_kernel(
    const float* __restrict__ x, const uint4* __restrict__ wp,
    const float* __restrict__ t, float* __restrict__ part) {
  __shared__ float  lt[NT];
  __shared__ float4 nA[16][8];    // N0..N3 per (local c, local b)
  __shared__ float  sA[16][8];    // silu(x)
  __shared__ int    bA[16][8];    // base row (i-3)
  __shared__ float  red[4][2048]; // per-wave partials: [wave][b*256 + o]

  const int tid = threadIdx.x;
  const unsigned bid = blockIdx.x;
  // cchunk = bid&15 -> 16 chunks of 16 channels. Dispatch round-robins
  // bid%8 across XCDs, so chunk k lives entirely on XCD k%8: per-XCD
  // working set = 2 chunks * 16c * 68 rows * 512 B = 1.1 MB (L2-resident).
  const int cchunk = bid & 15;
  const int bgroup = bid >> 4;    // 64 groups of 8 batch rows

  if (tid < NT) lt[tid] = t[tid];
  __syncthreads();

  // ---- Phase 1: basis for 8 b x 16 c; one (b,c) pair per thread ----
  if (tid < 128) {
    const int bb = tid >> 4;
    const int cl = tid & 15;
    const float xv = x[(size_t)(bgroup * 8 + bb) * IN_DIM + cchunk * 16 + cl];
    int i = 3 + (int)floorf((xv + 1.0f) * 32.0f);
    i = i < 3 ? 3 : (i > 66 ? 66 : i);
    while (i > 3 && xv < lt[i]) --i;
    while (i < 66 && xv >= lt[i + 1]) ++i;

    float N0 = 1.f, N1 = 0.f, N2 = 0.f, N3 = 0.f;
    { // p = 1
      const float l1 = xv - lt[i];
      const float r1 = lt[i + 1] - xv;
      const float tp = N0 / (r1 + l1);
      N1 = l1 * tp; N0 = r1 * tp;
    }
    { // p = 2
      const float l1 = xv - lt[i];
      const float l2 = xv - lt[i - 1];
      const float r1 = lt[i + 1] - xv;
      const float r2 = lt[i + 2] - xv;
      float saved = 0.f;
      const float tp0 = N0 / (r1 + l2);
      const float n0 = saved + r1 * tp0; saved = l2 * tp0;
      const float tp1 = N1 / (r2 + l1);
      const float n1 = saved + r2 * tp1; saved = l1 * tp1;
      N0 = n0; N1 = n1; N2 = saved;
    }
    { // p = 3
      const float l1 = xv - lt[i];
      const float l2 = xv - lt[i - 1];
      const float l3 = xv - lt[i - 2];
      const float r1 = lt[i + 1] - xv;
      const float r2 = lt[i + 2] - xv;
      const float r3 = lt[i + 3] - xv;
      float saved = 0.f;
      const float tp0 = N0 / (r1 + l3);
      const float n0 = saved + r1 * tp0; saved = l3 * tp0;
      const float tp1 = N1 / (r2 + l2);
      const float n1 = saved + r2 * tp1; saved = l2 * tp1;
      const float tp2 = N2 / (r3 + l1);
      const float n2 = saved + r3 * tp2; saved = l1 * tp2;
      N0 = n0; N1 = n1; N2 = n2; N3 = saved;
    }
    nA[cl][bb] = make_float4(N0, N1, N2, N3);
    sA[cl][bb] = xv / (1.0f + expf(-xv));
    bA[cl][bb] = i - 3;
  }
  __syncthreads();

  // ---- Phase 2: wave = 2 channels/pass (half-wave each), 2 passes ->
  //      4 channels/wave. Per channel: silu row + 8 b x 4 rows; compiler
  //      schedules the loads across the unrolled b-loop. ----
  const int wv   = tid >> 6;
  const int lane = tid & 63;
  const int half = lane >> 5;
  const int ol   = lane & 31;     // uint4 (8-o) slot: o = ol*8 + j

  float acc[8][8];
  #pragma unroll
  for (int b = 0; b < 8; ++b) {
    #pragma unroll
    for (int j = 0; j < 8; ++j) acc[b][j] = 0.f;
  }

  for (int pp = 0; pp < 2; ++pp) {
    const int cl = wv * 4 + pp * 2 + half;            // local c, 0..15
    const uint32_t cbase = (uint32_t)((cchunk * 16 + cl) * 32 + ol);
    const uint4 q4 = wp[cbase + 67u * 8192u];         // silu row: once per c
    #pragma unroll
    for (int b = 0; b < 8; ++b) {
      const float4 yv = nA[cl][b];
      const float  ys = sA[cl][b];
      const uint32_t rb = cbase + ((uint32_t)bA[cl][b] << 13);
      const uint4 q0 = wp[rb];
      const uint4 q1 = wp[rb +  8192u];
      const uint4 q2 = wp[rb + 16384u];
      const uint4 q3 = wp[rb + 24576u];
      fma8(q0, yv.x, acc[b]);
      fma8(q1, yv.y, acc[b]);
      fma8(q2, yv.z, acc[b]);
      fma8(q3, yv.w, acc[b]);
      fma8(q4, ys,   acc[b]);
    }
  }

  // fold the two half-waves (partner lane holds the pass's other channel)
  #pragma unroll
  for (int b = 0; b < 8; ++b) {
    #pragma unroll
    for (int j = 0; j < 8; ++j)
      acc[b][j] += __shfl_xor(acc[b][j], 32, 64);
  }

  if (half == 0) {
    #pragma unroll
    for (int b = 0; b < 8; ++b) {
      #pragma unroll
      for (int j = 0; j < 8; ++j)
        red[wv][b * 256 + ol * 8 + j] = acc[b][j];
    }
  }
  __syncthreads();

  // ---- Phase 3: sum the 4 waves, store c-chunk partial (streaming) ----
  {
    const int b  = tid >> 5;         // local batch row
    const int oo = tid & 31;         // 8-float slot
    float s[8] = {0.f, 0.f, 0.f, 0.f, 0.f, 0.f, 0.f, 0.f};
    #pragma unroll
    for (int w2 = 0; w2 < 4; ++w2) {
      const float* rr = &red[w2][b * 256 + oo * 8];
      #pragma unroll
      for (int j = 0; j < 8; ++j) s[j] += rr[j];
    }
    float* dst = part + ((size_t)cchunk * BATCH + bgroup * 8 + b) * OUT_DIM + oo * 8;
    *(float4*)dst       = make_float4(s[0], s[1], s[2], s[3]);
    *(float4*)(dst + 4) = make_float4(s[4], s[5], s[6], s[7]);
  }
}

// ---- Kernel C: reduce the 16 c-chunk partials into out ----
__global__ __launch_bounds__(256) void reduce_kernel(const float* __restrict__ part,
                                                     float* __restrict__ out) {
  const int q = blockIdx.x * 256 + threadIdx.x;   // float4 index, 32768 total
  const int S = BATCH * OUT_DIM / 4;              // float4 stride per slice
  const float4* p = (const float4*)part;
  float4 s = p[q];
  #pragma unroll
  for (int k = 1; k < 16; ++k) {
    const float4 a = p[q + k * S];
    s.x += a.x; s.y += a.y; s.z += a.z; s.w += a.w;
  }
  ((float4*)out)[q] = s;
}

extern "C" void kernel_launch(void* const* d_in, const int* in_sizes, int n_in,
                              void* d_out, int out_size, void* d_ws, size_t ws_size,
                              hipStream_t stream) {
  const float* x = (const float*)d_in[0];
  const float* w = (const float*)d_in[1];
  const float* t = (const float*)d_in[2];
  float* out  = (float*)d_out;
  float* part = (float*)d_ws;                       // 8 MB of partials
  uint32_t* wb = (uint32_t*)d_ws + PART_FLOATS;     // bf16 weights after
  cvt_kernel<<<W_ELEMS / (256 * 8), 256, 0, stream>>>(w, wb);
  kan_gather_kernel<<<1024, 256, 0, stream>>>(x, (const uint4*)wb, t, part);
  reduce_kernel<<<BATCH * OUT_DIM / 4 / 256, 256, 0, stream>>>(part, out);
}

// Round 6
// 98.146 us; speedup vs baseline: 1.0276x; 1.0276x over previous
//
#include <hip/hip_runtime.h>
#include <math.h>
#include <stdint.h>

#define IN_DIM  256
#define OUT_DIM 256
#define NROWS   68     // G + K
#define NT      71     // knot count
#define BATCH   512
#define W_ELEMS (NROWS * IN_DIM * OUT_DIM)   // 4,456,448
#define PART_FLOATS (8 * BATCH * OUT_DIM)    // 8 c-chunk slices = 4 MB

// ---- Kernel A: convert w fp32 -> packed bf16 pairs (streaming, ~4.5 us) ----
__device__ __forceinline__ uint32_t bf16_rne(float f) {
  uint32_t u = __builtin_bit_cast(uint32_t, f);
  return (u + 0x7fffu + ((u >> 16) & 1u)) >> 16;   // finite inputs only
}

__global__ __launch_bounds__(256) void cvt_kernel(const float* __restrict__ w,
                                                  uint32_t* __restrict__ wb) {
  const int base = (blockIdx.x * 256 + threadIdx.x) * 8;   // 8 floats / thread
  const float4 a = *(const float4*)(w + base);
  const float4 b = *(const float4*)(w + base + 4);
  uint4 o;
  o.x = bf16_rne(a.x) | (bf16_rne(a.y) << 16);
  o.y = bf16_rne(a.z) | (bf16_rne(a.w) << 16);
  o.z = bf16_rne(b.x) | (bf16_rne(b.y) << 16);
  o.w = bf16_rne(b.z) | (bf16_rne(b.w) << 16);
  *(uint4*)(wb + base / 2) = o;
}

// ---- Kernel B: bf16 gather-accumulate.
//      Block = 4 batch rows x 32 channels, grid 1024. acc[4][8] = 32 VGPRs
//      -> whole kernel fits ~90 VGPRs -> launch_bounds(256,4) gives a real
//      4 blocks/CU (16 waves/CU, 2x R1) with NO spills (R4/R5 spilled).
//      Inner loop is R1's proven compiler-scheduled form (no manual
//      ping-pong, no hoisted scalar bloat). ----
__device__ __forceinline__ void fma8(const uint4 q, const float y, float* acc) {
  acc[0] += y * __builtin_bit_cast(float, q.x << 16);
  acc[1] += y * __builtin_bit_cast(float, q.x & 0xffff0000u);
  acc[2] += y * __builtin_bit_cast(float, q.y << 16);
  acc[3] += y * __builtin_bit_cast(float, q.y & 0xffff0000u);
  acc[4] += y * __builtin_bit_cast(float, q.z << 16);
  acc[5] += y * __builtin_bit_cast(float, q.z & 0xffff0000u);
  acc[6] += y * __builtin_bit_cast(float, q.w << 16);
  acc[7] += y * __builtin_bit_cast(float, q.w & 0xffff0000u);
}

__global__ __launch_bounds__(256, 4) void kan_gather_kernel(
    const float* __restrict__ x, const uint4* __restrict__ wp,
    const float* __restrict__ t, float* __restrict__ part) {
  __shared__ float  lt[NT];
  __shared__ float4 nA[32][4];    // N0..N3 per (local c, local b)
  __shared__ float  sA[32][4];    // silu(x)
  __shared__ int    bA[32][4];    // base row (i-3)
  __shared__ float  red[4][1024]; // per-wave partials: [wave][b*256 + o]

  const int tid = threadIdx.x;
  const unsigned bid = blockIdx.x;
  // cchunk = bid&7 -> XCD affinity (dispatch round-robins bid%8): each XCD's
  // L2 holds only its 32-channel bf16 slice (68*32*512B = 1.1 MB).
  const int cchunk = bid & 7;
  const int bgroup = bid >> 3;    // 128 groups of 4 batch rows

  if (tid < NT) lt[tid] = t[tid];
  __syncthreads();

  // ---- Phase 1: basis for 4 b x 32 c; one (b,c) pair per thread ----
  if (tid < 128) {
    const int bb = tid >> 5;
    const int cl = tid & 31;
    const float xv = x[(size_t)(bgroup * 4 + bb) * IN_DIM + cchunk * 32 + cl];
    int i = 3 + (int)floorf((xv + 1.0f) * 32.0f);
    i = i < 3 ? 3 : (i > 66 ? 66 : i);
    while (i > 3 && xv < lt[i]) --i;
    while (i < 66 && xv >= lt[i + 1]) ++i;

    float N0 = 1.f, N1 = 0.f, N2 = 0.f, N3 = 0.f;
    { // p = 1
      const float l1 = xv - lt[i];
      const float r1 = lt[i + 1] - xv;
      const float tp = N0 / (r1 + l1);
      N1 = l1 * tp; N0 = r1 * tp;
    }
    { // p = 2
      const float l1 = xv - lt[i];
      const float l2 = xv - lt[i - 1];
      const float r1 = lt[i + 1] - xv;
      const float r2 = lt[i + 2] - xv;
      float saved = 0.f;
      const float tp0 = N0 / (r1 + l2);
      const float n0 = saved + r1 * tp0; saved = l2 * tp0;
      const float tp1 = N1 / (r2 + l1);
      const float n1 = saved + r2 * tp1; saved = l1 * tp1;
      N0 = n0; N1 = n1; N2 = saved;
    }
    { // p = 3
      const float l1 = xv - lt[i];
      const float l2 = xv - lt[i - 1];
      const float l3 = xv - lt[i - 2];
      const float r1 = lt[i + 1] - xv;
      const float r2 = lt[i + 2] - xv;
      const float r3 = lt[i + 3] - xv;
      float saved = 0.f;
      const float tp0 = N0 / (r1 + l3);
      const float n0 = saved + r1 * tp0; saved = l3 * tp0;
      const float tp1 = N1 / (r2 + l2);
      const float n1 = saved + r2 * tp1; saved = l2 * tp1;
      const float tp2 = N2 / (r3 + l1);
      const float n2 = saved + r3 * tp2; saved = l1 * tp2;
      N0 = n0; N1 = n1; N2 = n2; N3 = saved;
    }
    nA[cl][bb] = make_float4(N0, N1, N2, N3);
    sA[cl][bb] = xv / (1.0f + expf(-xv));
    bA[cl][bb] = i - 3;
  }
  __syncthreads();

  // ---- Phase 2: wave = 2 channels/pass (half-wave each), 4 passes ->
  //      8 channels/wave. Per channel: silu row + 4 b x 4 rows; the
  //      compiler schedules loads across the unrolled b-loop. ----
  const int wv   = tid >> 6;
  const int lane = tid & 63;
  const int half = lane >> 5;
  const int ol   = lane & 31;     // uint4 (8-o) slot: o = ol*8 + j

  float acc[4][8];
  #pragma unroll
  for (int b = 0; b < 4; ++b) {
    #pragma unroll
    for (int j = 0; j < 8; ++j) acc[b][j] = 0.f;
  }

  for (int pp = 0; pp < 4; ++pp) {
    const int cl = wv * 8 + pp * 2 + half;            // local c, 0..31
    const uint32_t cbase = (uint32_t)((cchunk * 32 + cl) * 32 + ol);
    const uint4 q4 = wp[cbase + 67u * 8192u];         // silu row: once per c
    #pragma unroll
    for (int b = 0; b < 4; ++b) {
      const float4 yv = nA[cl][b];
      const float  ys = sA[cl][b];
      const uint32_t rb = cbase + ((uint32_t)bA[cl][b] << 13);
      const uint4 q0 = wp[rb];
      const uint4 q1 = wp[rb +  8192u];
      const uint4 q2 = wp[rb + 16384u];
      const uint4 q3 = wp[rb + 24576u];
      fma8(q0, yv.x, acc[b]);
      fma8(q1, yv.y, acc[b]);
      fma8(q2, yv.z, acc[b]);
      fma8(q3, yv.w, acc[b]);
      fma8(q4, ys,   acc[b]);
    }
  }

  // fold the two half-waves (partner lane holds the pass's other channel)
  #pragma unroll
  for (int b = 0; b < 4; ++b) {
    #pragma unroll
    for (int j = 0; j < 8; ++j)
      acc[b][j] += __shfl_xor(acc[b][j], 32, 64);
  }

  if (half == 0) {
    #pragma unroll
    for (int b = 0; b < 4; ++b) {
      #pragma unroll
      for (int j = 0; j < 8; ++j)
        red[wv][b * 256 + ol * 8 + j] = acc[b][j];
    }
  }
  __syncthreads();

  // ---- Phase 3: sum the 4 waves, store c-chunk partial (streaming) ----
  {
    const int b  = tid >> 6;        // local batch row, 0..3
    const int o4 = tid & 63;        // float4 slot over 256 outputs
    const float4 a0 = *(const float4*)&red[0][b * 256 + o4 * 4];
    const float4 a1 = *(const float4*)&red[1][b * 256 + o4 * 4];
    const float4 a2 = *(const float4*)&red[2][b * 256 + o4 * 4];
    const float4 a3 = *(const float4*)&red[3][b * 256 + o4 * 4];
    float4 s;
    s.x = (a0.x + a1.x) + (a2.x + a3.x);
    s.y = (a0.y + a1.y) + (a2.y + a3.y);
    s.z = (a0.z + a1.z) + (a2.z + a3.z);
    s.w = (a0.w + a1.w) + (a2.w + a3.w);
    *(float4*)(part + ((size_t)cchunk * BATCH + bgroup * 4 + b) * OUT_DIM + o4 * 4) = s;
  }
}

// ---- Kernel C: reduce the 8 c-chunk partials into out ----
__global__ __launch_bounds__(256) void reduce_kernel(const float* __restrict__ part,
                                                     float* __restrict__ out) {
  const int q = blockIdx.x * 256 + threadIdx.x;   // float4 index, 32768 total
  const int S = BATCH * OUT_DIM / 4;              // float4 stride per slice
  const float4* p = (const float4*)part;
  float4 s = p[q];
  #pragma unroll
  for (int k = 1; k < 8; ++k) {
    const float4 a = p[q + k * S];
    s.x += a.x; s.y += a.y; s.z += a.z; s.w += a.w;
  }
  ((float4*)out)[q] = s;
}

extern "C" void kernel_launch(void* const* d_in, const int* in_sizes, int n_in,
                              void* d_out, int out_size, void* d_ws, size_t ws_size,
                              hipStream_t stream) {
  const float* x = (const float*)d_in[0];
  const float* w = (const float*)d_in[1];
  const float* t = (const float*)d_in[2];
  float* out  = (float*)d_out;
  float* part = (float*)d_ws;                       // 4 MB of partials
  uint32_t* wb = (uint32_t*)d_ws + PART_FLOATS;     // bf16 weights after
  cvt_kernel<<<W_ELEMS / (256 * 8), 256, 0, stream>>>(w, wb);
  kan_gather_kernel<<<1024, 256, 0, stream>>>(x, (const uint4*)wb, t, part);
  reduce_kernel<<<BATCH * OUT_DIM / 4 / 256, 256, 0, stream>>>(part, out);
}

// Round 7
// 89.391 us; speedup vs baseline: 1.1282x; 1.0979x over previous
//
#include <hip/hip_runtime.h>
#include <math.h>
#include <stdint.h>

#define IN_DIM  256
#define OUT_DIM 256
#define NROWS   68     // G + K
#define NT      71     // knot count
#define BATCH   512
#define W_ELEMS (NROWS * IN_DIM * OUT_DIM)   // 4,456,448
#define PART_FLOATS (8 * BATCH * OUT_DIM)    // 1,048,576 floats = 4 MB

// ---- Kernel A: convert w fp32 -> packed bf16 pairs ----
__device__ __forceinline__ uint32_t bf16_rne(float f) {
  uint32_t u = __builtin_bit_cast(uint32_t, f);
  return (u + 0x7fffu + ((u >> 16) & 1u)) >> 16;   // finite inputs only
}

__global__ __launch_bounds__(256) void cvt_kernel(const float* __restrict__ w,
                                                  uint32_t* __restrict__ wb) {
  const int base = (blockIdx.x * 256 + threadIdx.x) * 8;   // 8 floats / thread
  const float4 a = *(const float4*)(w + base);
  const float4 b = *(const float4*)(w + base + 4);
  uint4 o;
  o.x = bf16_rne(a.x) | (bf16_rne(a.y) << 16);
  o.y = bf16_rne(a.z) | (bf16_rne(a.w) << 16);
  o.z = bf16_rne(b.x) | (bf16_rne(b.y) << 16);
  o.w = bf16_rne(b.z) | (bf16_rne(b.w) << 16);
  *(uint4*)(wb + base / 2) = o;
}

// ---- Kernel B: bf16 gather-accumulate. EXACT R1 configuration (8 b x 32 c,
//      grid 512, no min-waves cap, ~2 waves/SIMD) with ONE change: each pass
//      issues ALL 33 row loads (silu + 8 b x 4 rows) into registers BEFORE
//      any FMA. Dependency distance grows from ~400 to ~3200 cycles -> L2
//      latency fully hidden; gather approaches its TA-issue floor. ----
__device__ __forceinline__ void fma8(const uint4 q, const float y, float* acc) {
  acc[0] += y * __builtin_bit_cast(float, q.x << 16);
  acc[1] += y * __builtin_bit_cast(float, q.x & 0xffff0000u);
  acc[2] += y * __builtin_bit_cast(float, q.y << 16);
  acc[3] += y * __builtin_bit_cast(float, q.y & 0xffff0000u);
  acc[4] += y * __builtin_bit_cast(float, q.z << 16);
  acc[5] += y * __builtin_bit_cast(float, q.z & 0xffff0000u);
  acc[6] += y * __builtin_bit_cast(float, q.w << 16);
  acc[7] += y * __builtin_bit_cast(float, q.w & 0xffff0000u);
}

__global__ __launch_bounds__(256) void kan_gather_kernel(
    const float* __restrict__ x, const uint4* __restrict__ wp,
    const float* __restrict__ t, float* __restrict__ part) {
  __shared__ float  lt[NT];
  __shared__ float4 nA[32][8];   // N0..N3 per (local c, local b)
  __shared__ float  sA[32][8];   // silu(x)
  __shared__ int    bA[32][8];   // base row (i-3)
  __shared__ float  red[4][2048]; // per-wave partials: [wave][b*256 + o]

  const int tid = threadIdx.x;
  const unsigned bid = blockIdx.x;
  // cchunk = bid&7 -> XCD affinity (dispatch round-robins bid%8): each XCD's
  // L2 holds only its 32-channel bf16 slice (68*32*512B = 1.1 MB).
  const int cchunk = bid & 7;
  const int bgroup = bid >> 3;   // 64 groups of 8 batch rows

  if (tid < NT) lt[tid] = t[tid];
  __syncthreads();

  // ---- Phase 1: basis for 8 b x 32 c; exactly one (b,c) pair per thread ----
  {
    const int bb = tid >> 5;
    const int cl = tid & 31;
    const float xv = x[(size_t)(bgroup * 8 + bb) * IN_DIM + cchunk * 32 + cl];
    int i = 3 + (int)floorf((xv + 1.0f) * 32.0f);
    i = i < 3 ? 3 : (i > 66 ? 66 : i);
    while (i > 3 && xv < lt[i]) --i;
    while (i < 66 && xv >= lt[i + 1]) ++i;

    float N0 = 1.f, N1 = 0.f, N2 = 0.f, N3 = 0.f;
    { // p = 1
      const float l1 = xv - lt[i];
      const float r1 = lt[i + 1] - xv;
      const float tp = N0 / (r1 + l1);
      N1 = l1 * tp; N0 = r1 * tp;
    }
    { // p = 2
      const float l1 = xv - lt[i];
      const float l2 = xv - lt[i - 1];
      const float r1 = lt[i + 1] - xv;
      const float r2 = lt[i + 2] - xv;
      float saved = 0.f;
      const float tp0 = N0 / (r1 + l2);
      const float n0 = saved + r1 * tp0; saved = l2 * tp0;
      const float tp1 = N1 / (r2 + l1);
      const float n1 = saved + r2 * tp1; saved = l1 * tp1;
      N0 = n0; N1 = n1; N2 = saved;
    }
    { // p = 3
      const float l1 = xv - lt[i];
      const float l2 = xv - lt[i - 1];
      const float l3 = xv - lt[i - 2];
      const float r1 = lt[i + 1] - xv;
      const float r2 = lt[i + 2] - xv;
      const float r3 = lt[i + 3] - xv;
      float saved = 0.f;
      const float tp0 = N0 / (r1 + l3);
      const float n0 = saved + r1 * tp0; saved = l3 * tp0;
      const float tp1 = N1 / (r2 + l2);
      const float n1 = saved + r2 * tp1; saved = l2 * tp1;
      const float tp2 = N2 / (r3 + l1);
      const float n2 = saved + r3 * tp2; saved = l1 * tp2;
      N0 = n0; N1 = n1; N2 = n2; N3 = saved;
    }
    nA[cl][bb] = make_float4(N0, N1, N2, N3);
    sA[cl][bb] = xv / (1.0f + expf(-xv));
    bA[cl][bb] = i - 3;
  }
  __syncthreads();

  // ---- Phase 2: wave = 2 channels/pass (half-wave each, 32 lanes x uint4 =
  //      full 256-o bf16 row), 4 passes. Per pass: batch-issue 33 loads,
  //      then all FMAs. ----
  const int wv   = tid >> 6;
  const int lane = tid & 63;
  const int half = lane >> 5;
  const int ol   = lane & 31;     // uint4 (8-o) slot: o = ol*8 + j

  float acc[8][8];
  #pragma unroll
  for (int b = 0; b < 8; ++b) {
    #pragma unroll
    for (int j = 0; j < 8; ++j) acc[b][j] = 0.f;
  }

  for (int pp = 0; pp < 4; ++pp) {
    const int cl = wv * 8 + pp * 2 + half;            // local c, 0..31
    const uint32_t cbase = (uint32_t)((cchunk * 32 + cl) * 32 + ol);
    const uint4 q4 = wp[cbase + 67u * 8192u];         // silu row

    // batch-issue: all 32 spline-row loads, no intervening VALU use
    uint4 q[8][4];
    #pragma unroll
    for (int b = 0; b < 8; ++b) {
      const uint32_t rb = cbase + ((uint32_t)bA[cl][b] << 13);
      q[b][0] = wp[rb];
      q[b][1] = wp[rb +  8192u];
      q[b][2] = wp[rb + 16384u];
      q[b][3] = wp[rb + 24576u];
    }
    // consume: ~1600 VALU cycles, loads long since landed
    #pragma unroll
    for (int b = 0; b < 8; ++b) {
      const float4 yv = nA[cl][b];
      const float  ys = sA[cl][b];
      fma8(q[b][0], yv.x, acc[b]);
      fma8(q[b][1], yv.y, acc[b]);
      fma8(q[b][2], yv.z, acc[b]);
      fma8(q[b][3], yv.w, acc[b]);
      fma8(q4,      ys,   acc[b]);
    }
  }

  // fold the two half-waves (partner lane holds the pass's other channel)
  #pragma unroll
  for (int b = 0; b < 8; ++b) {
    #pragma unroll
    for (int j = 0; j < 8; ++j)
      acc[b][j] += __shfl_xor(acc[b][j], 32, 64);
  }

  if (half == 0) {
    #pragma unroll
    for (int b = 0; b < 8; ++b) {
      #pragma unroll
      for (int j = 0; j < 8; ++j)
        red[wv][b * 256 + ol * 8 + j] = acc[b][j];
    }
  }
  __syncthreads();

  // ---- Phase 3: sum the 4 waves, store c-chunk partial (streaming) ----
  {
    const int b  = tid >> 5;         // local batch row
    const int oo = tid & 31;         // 8-float slot
    float s[8] = {0.f, 0.f, 0.f, 0.f, 0.f, 0.f, 0.f, 0.f};
    #pragma unroll
    for (int w2 = 0; w2 < 4; ++w2) {
      const float* rr = &red[w2][b * 256 + oo * 8];
      #pragma unroll
      for (int j = 0; j < 8; ++j) s[j] += rr[j];
    }
    float* dst = part + ((size_t)cchunk * BATCH + bgroup * 8 + b) * OUT_DIM + oo * 8;
    *(float4*)dst       = make_float4(s[0], s[1], s[2], s[3]);
    *(float4*)(dst + 4) = make_float4(s[4], s[5], s[6], s[7]);
  }
}

// ---- Kernel C: reduce the 8 c-chunk partials into out ----
__global__ __launch_bounds__(256) void reduce_kernel(const float* __restrict__ part,
                                                     float* __restrict__ out) {
  const int q = blockIdx.x * 256 + threadIdx.x;   // float4 index, 32768 total
  const int S = BATCH * OUT_DIM / 4;              // float4 stride per slice
  const float4* p = (const float4*)part;
  float4 s = p[q];
  #pragma unroll
  for (int k = 1; k < 8; ++k) {
    const float4 a = p[q + k * S];
    s.x += a.x; s.y += a.y; s.z += a.z; s.w += a.w;
  }
  ((float4*)out)[q] = s;
}

extern "C" void kernel_launch(void* const* d_in, const int* in_sizes, int n_in,
                              void* d_out, int out_size, void* d_ws, size_t ws_size,
                              hipStream_t stream) {
  const float* x = (const float*)d_in[0];
  const float* w = (const float*)d_in[1];
  const float* t = (const float*)d_in[2];
  float* out  = (float*)d_out;
  float* part = (float*)d_ws;                       // 4 MB of partials
  uint32_t* wb = (uint32_t*)d_ws + PART_FLOATS;     // bf16 weights after
  cvt_kernel<<<W_ELEMS / (256 * 8), 256, 0, stream>>>(w, wb);
  kan_gather_kernel<<<BATCH / 8 * 8, 256, 0, stream>>>(x, (const uint4*)wb, t, part);
  reduce_kernel<<<BATCH * OUT_DIM / 4 / 256, 256, 0, stream>>>(part, out);
}